// Round 1
// baseline (123.211 us; speedup 1.0000x reference)
//
#include <hip/hip_runtime.h>
#include <hip/hip_bf16.h>

#define IN_F 4096
#define LOCAL_F 128
#define KSZ 64
#define STRIDE_ 32
#define FOLDS 127
#define BATCH_ 4096
#define OUT_F (FOLDS * LOCAL_F)   // 16256

#define BM 64
#define NF 4
#define XCOLS (NF * STRIDE_ + (KSZ - STRIDE_))   // 160
#define LDSP 168                                  // padded bf16 stride (84 dwords -> conflict-free)

typedef __attribute__((ext_vector_type(8))) short bf16x8;
typedef __attribute__((ext_vector_type(4))) float f32x4;

__device__ __forceinline__ unsigned short f2bf(float f) {
    unsigned u = __builtin_bit_cast(unsigned, f);
    u += 0x7fffu + ((u >> 16) & 1u);   // round-to-nearest-even
    return (unsigned short)(u >> 16);
}

__global__ __launch_bounds__(256, 2)
void local_linear_kernel(const float* __restrict__ x,
                         const float* __restrict__ W,
                         const float* __restrict__ b,
                         float* __restrict__ out) {
    __shared__ unsigned short xs[BM][LDSP];

    const int bg = blockIdx.x;           // batch block 0..63
    const int fg = blockIdx.y;           // fold group 0..31
    const int row0 = bg * BM;
    const int col0 = fg * (NF * STRIDE_);

    const int t = threadIdx.x;

    // ---- stage x tile (BM x XCOLS) fp32 -> bf16 into LDS, coalesced float4 ----
    #pragma unroll
    for (int it = 0; it < (BM * (XCOLS / 4)) / 256; ++it) {
        int i  = t + it * 256;
        int r  = i / (XCOLS / 4);
        int c4 = i - r * (XCOLS / 4);
        int gcol = col0 + c4 * 4;
        float4 v = make_float4(0.f, 0.f, 0.f, 0.f);
        if (gcol < IN_F) {   // gcol multiple of 4, so this covers gcol+3 too
            v = *reinterpret_cast<const float4*>(x + (size_t)(row0 + r) * IN_F + gcol);
        }
        ushort4 s;
        s.x = f2bf(v.x); s.y = f2bf(v.y); s.z = f2bf(v.z); s.w = f2bf(v.w);
        *reinterpret_cast<ushort4*>(&xs[r][c4 * 4]) = s;
    }
    __syncthreads();

    const int wave = t >> 6;             // 0..3 -> fold within group
    const int lane = t & 63;
    const int f = fg * NF + wave;
    if (f >= FOLDS) return;              // tail group: wave 3 idles (after sync)

    const int l16 = lane & 15;
    const int g   = lane >> 4;

    f32x4 acc[4][8];
    #pragma unroll
    for (int mt = 0; mt < 4; ++mt)
        #pragma unroll
        for (int nt = 0; nt < 8; ++nt)
            acc[mt][nt] = (f32x4){0.f, 0.f, 0.f, 0.f};

    const float* Wf = W + (size_t)f * (LOCAL_F * KSZ);
    const int fcol = wave * STRIDE_;     // fold's column offset within LDS tile

    #pragma unroll
    for (int ks = 0; ks < 2; ++ks) {
        // B fragments: lane holds W[f][nt*16 + l16][ks*32 + g*8 + 0..7]  (L2-resident)
        bf16x8 wf[8];
        #pragma unroll
        for (int nt = 0; nt < 8; ++nt) {
            const float* p = Wf + (nt * 16 + l16) * KSZ + ks * 32 + g * 8;
            float4 va = *reinterpret_cast<const float4*>(p);
            float4 vb = *reinterpret_cast<const float4*>(p + 4);
            bf16x8 w8;
            w8[0] = (short)f2bf(va.x); w8[1] = (short)f2bf(va.y);
            w8[2] = (short)f2bf(va.z); w8[3] = (short)f2bf(va.w);
            w8[4] = (short)f2bf(vb.x); w8[5] = (short)f2bf(vb.y);
            w8[6] = (short)f2bf(vb.z); w8[7] = (short)f2bf(vb.w);
            wf[nt] = w8;
        }
        // A fragments from LDS: lane holds x[mt*16 + l16][fcol + ks*32 + g*8 + 0..7]
        bf16x8 af[4];
        #pragma unroll
        for (int mt = 0; mt < 4; ++mt) {
            af[mt] = *reinterpret_cast<const bf16x8*>(&xs[mt * 16 + l16][fcol + ks * 32 + g * 8]);
        }
        #pragma unroll
        for (int mt = 0; mt < 4; ++mt)
            #pragma unroll
            for (int nt = 0; nt < 8; ++nt)
                acc[mt][nt] = __builtin_amdgcn_mfma_f32_16x16x32_bf16(af[mt], wf[nt], acc[mt][nt], 0, 0, 0);
    }

    // ---- epilogue: bias + store. C/D: col = lane&15, row = 4*(lane>>4)+j ----
    #pragma unroll
    for (int nt = 0; nt < 8; ++nt) {
        const int gcol = f * LOCAL_F + nt * 16 + l16;
        const float bv = b[f * LOCAL_F + nt * 16 + l16];
        #pragma unroll
        for (int mt = 0; mt < 4; ++mt) {
            #pragma unroll
            for (int j = 0; j < 4; ++j) {
                const int grow = row0 + mt * 16 + g * 4 + j;
                out[(size_t)grow * OUT_F + gcol] = acc[mt][nt][j] + bv;
            }
        }
    }
}

extern "C" void kernel_launch(void* const* d_in, const int* in_sizes, int n_in,
                              void* d_out, int out_size, void* d_ws, size_t ws_size,
                              hipStream_t stream) {
    const float* x = (const float*)d_in[0];
    const float* W = (const float*)d_in[1];
    const float* b = (const float*)d_in[2];
    float* out = (float*)d_out;
    dim3 grid(BATCH_ / BM, (FOLDS + NF - 1) / NF);
    local_linear_kernel<<<grid, 256, 0, stream>>>(x, W, b, out);
}

// Round 2
// 117.712 us; speedup vs baseline: 1.0467x; 1.0467x over previous
//
#include <hip/hip_runtime.h>
#include <hip/hip_bf16.h>

#define IN_F 4096
#define LOCAL_F 128
#define KSZ 64
#define STRIDE_ 32
#define FOLDS 127
#define BATCH_ 4096
#define OUT_F (FOLDS * LOCAL_F)   // 16256
#define WN (FOLDS * LOCAL_F * KSZ) // 1040384 elements

#define BM 64
#define NF 4
#define XCOLS (NF * STRIDE_ + (KSZ - STRIDE_))   // 160
#define LDSP 168                                  // padded bf16 stride

typedef __attribute__((ext_vector_type(8))) short bf16x8;
typedef __attribute__((ext_vector_type(8))) unsigned short u16x8;
typedef __attribute__((ext_vector_type(4))) float f32x4;

__device__ __forceinline__ unsigned short f2bf(float f) {
    unsigned u = __builtin_bit_cast(unsigned, f);
    u += 0x7fffu + ((u >> 16) & 1u);   // round-to-nearest-even
    return (unsigned short)(u >> 16);
}

// ---- prep: W fp32 -> bf16 into workspace (once per launch, 4MB read / 2MB write) ----
__global__ __launch_bounds__(256)
void wprep_kernel(const float* __restrict__ W, unsigned short* __restrict__ Wbf) {
    int i = (blockIdx.x * 256 + threadIdx.x) * 8;
    if (i >= WN) return;
    float4 a = *reinterpret_cast<const float4*>(W + i);
    float4 c = *reinterpret_cast<const float4*>(W + i + 4);
    u16x8 s;
    s[0] = f2bf(a.x); s[1] = f2bf(a.y); s[2] = f2bf(a.z); s[3] = f2bf(a.w);
    s[4] = f2bf(c.x); s[5] = f2bf(c.y); s[6] = f2bf(c.z); s[7] = f2bf(c.w);
    *reinterpret_cast<u16x8*>(Wbf + i) = s;
}

template<bool WB>
__global__ __launch_bounds__(256, 2)
void local_linear_kernel(const float* __restrict__ x,
                         const float* __restrict__ Wf32,
                         const unsigned short* __restrict__ Wbf,
                         const float* __restrict__ b,
                         float* __restrict__ out) {
    __shared__ unsigned short xs[BM][LDSP];

    const int bg = blockIdx.x;           // batch block 0..63
    const int fg = blockIdx.y;           // fold group 0..31
    const int row0 = bg * BM;
    const int col0 = fg * (NF * STRIDE_);

    const int t = threadIdx.x;

    // ---- stage x tile (BM x XCOLS) fp32 -> bf16 into LDS ----
    #pragma unroll
    for (int it = 0; it < (BM * (XCOLS / 4)) / 256; ++it) {
        int i  = t + it * 256;
        int r  = i / (XCOLS / 4);
        int c4 = i - r * (XCOLS / 4);
        int gcol = col0 + c4 * 4;
        float4 v = make_float4(0.f, 0.f, 0.f, 0.f);
        if (gcol < IN_F) {
            v = *reinterpret_cast<const float4*>(x + (size_t)(row0 + r) * IN_F + gcol);
        }
        ushort4 s;
        s.x = f2bf(v.x); s.y = f2bf(v.y); s.z = f2bf(v.z); s.w = f2bf(v.w);
        *reinterpret_cast<ushort4*>(&xs[r][c4 * 4]) = s;
    }
    __syncthreads();

    const int wave = t >> 6;             // fold within group
    const int lane = t & 63;
    const int f = fg * NF + wave;
    if (f >= FOLDS) return;              // tail: wave 3 idles (after sync)

    const int l16 = lane & 15;
    const int g   = lane >> 4;

    f32x4 acc[4][8];
    #pragma unroll
    for (int mt = 0; mt < 4; ++mt)
        #pragma unroll
        for (int nt = 0; nt < 8; ++nt)
            acc[mt][nt] = (f32x4){0.f, 0.f, 0.f, 0.f};

    const int fcol = wave * STRIDE_;

    #pragma unroll
    for (int ks = 0; ks < 2; ++ks) {
        // W fragment: lane holds W[f][nt*16 + l16][ks*32 + g*8 + 0..7]
        bf16x8 wf[8];
        #pragma unroll
        for (int nt = 0; nt < 8; ++nt) {
            if (WB) {
                wf[nt] = *reinterpret_cast<const bf16x8*>(
                    Wbf + ((size_t)f * LOCAL_F + nt * 16 + l16) * KSZ + ks * 32 + g * 8);
            } else {
                const float* p = Wf32 + ((size_t)f * LOCAL_F + nt * 16 + l16) * KSZ + ks * 32 + g * 8;
                float4 va = *reinterpret_cast<const float4*>(p);
                float4 vb = *reinterpret_cast<const float4*>(p + 4);
                bf16x8 w8;
                w8[0] = (short)f2bf(va.x); w8[1] = (short)f2bf(va.y);
                w8[2] = (short)f2bf(va.z); w8[3] = (short)f2bf(va.w);
                w8[4] = (short)f2bf(vb.x); w8[5] = (short)f2bf(vb.y);
                w8[6] = (short)f2bf(vb.z); w8[7] = (short)f2bf(vb.w);
                wf[nt] = w8;
            }
        }
        // x fragment from LDS: lane holds x[mt*16 + l16][fcol + ks*32 + g*8 + 0..7]
        bf16x8 af[4];
        #pragma unroll
        for (int mt = 0; mt < 4; ++mt) {
            af[mt] = *reinterpret_cast<const bf16x8*>(&xs[mt * 16 + l16][fcol + ks * 32 + g * 8]);
        }
        // D = W x X^T : lane holds D[feature = 4g+j][batch = l16]
        #pragma unroll
        for (int mt = 0; mt < 4; ++mt)
            #pragma unroll
            for (int nt = 0; nt < 8; ++nt)
                acc[mt][nt] = __builtin_amdgcn_mfma_f32_16x16x32_bf16(wf[nt], af[mt], acc[mt][nt], 0, 0, 0);
    }

    // ---- epilogue: bias + float4 stores ----
    // lane owns batch row (mt*16 + l16), features f*128 + nt*16 + 4g + 0..3
    f32x4 bv[8];
    #pragma unroll
    for (int nt = 0; nt < 8; ++nt)
        bv[nt] = *reinterpret_cast<const f32x4*>(b + (size_t)f * LOCAL_F + nt * 16 + 4 * g);

    #pragma unroll
    for (int mt = 0; mt < 4; ++mt) {
        float* orow = out + (size_t)(row0 + mt * 16 + l16) * OUT_F + f * LOCAL_F + 4 * g;
        #pragma unroll
        for (int nt = 0; nt < 8; ++nt) {
            f32x4 v = acc[mt][nt] + bv[nt];
            *reinterpret_cast<f32x4*>(orow + nt * 16) = v;
        }
    }
}

extern "C" void kernel_launch(void* const* d_in, const int* in_sizes, int n_in,
                              void* d_out, int out_size, void* d_ws, size_t ws_size,
                              hipStream_t stream) {
    const float* x = (const float*)d_in[0];
    const float* W = (const float*)d_in[1];
    const float* b = (const float*)d_in[2];
    float* out = (float*)d_out;
    dim3 grid(BATCH_ / BM, (FOLDS + NF - 1) / NF);

    if (ws_size >= (size_t)WN * sizeof(unsigned short)) {
        unsigned short* Wbf = (unsigned short*)d_ws;
        wprep_kernel<<<(WN / 8 + 255) / 256, 256, 0, stream>>>(W, Wbf);
        local_linear_kernel<true><<<grid, 256, 0, stream>>>(x, W, Wbf, b, out);
    } else {
        local_linear_kernel<false><<<grid, 256, 0, stream>>>(x, W, nullptr, b, out);
    }
}

// Round 3
// 103.007 us; speedup vs baseline: 1.1961x; 1.1428x over previous
//
#include <hip/hip_runtime.h>
#include <hip/hip_bf16.h>

#define IN_F 4096
#define LOCAL_F 128
#define KSZ 64
#define STRIDE_ 32
#define FOLDS 127
#define BATCH_ 4096
#define OUT_F (FOLDS * LOCAL_F)    // 16256
#define WN (FOLDS * LOCAL_F * KSZ) // 1040384 elements

#define BM 64
#define NF 2
#define XCOLS (NF * STRIDE_ + (KSZ - STRIDE_))   // 96
#define LDSP 104                                  // padded bf16 stride (52 dwords -> 2-way max, free)

typedef __attribute__((ext_vector_type(8))) short bf16x8;
typedef __attribute__((ext_vector_type(8))) unsigned short u16x8;
typedef __attribute__((ext_vector_type(4))) float f32x4;

__device__ __forceinline__ unsigned short f2bf(float f) {
    unsigned u = __builtin_bit_cast(unsigned, f);
    u += 0x7fffu + ((u >> 16) & 1u);   // round-to-nearest-even
    return (unsigned short)(u >> 16);
}

// ---- prep: W fp32 -> bf16 into workspace ----
__global__ __launch_bounds__(256)
void wprep_kernel(const float* __restrict__ W, unsigned short* __restrict__ Wbf) {
    int i = (blockIdx.x * 256 + threadIdx.x) * 8;
    if (i >= WN) return;
    float4 a = *reinterpret_cast<const float4*>(W + i);
    float4 c = *reinterpret_cast<const float4*>(W + i + 4);
    u16x8 s;
    s[0] = f2bf(a.x); s[1] = f2bf(a.y); s[2] = f2bf(a.z); s[3] = f2bf(a.w);
    s[4] = f2bf(c.x); s[5] = f2bf(c.y); s[6] = f2bf(c.z); s[7] = f2bf(c.w);
    *reinterpret_cast<u16x8*>(Wbf + i) = s;
}

__global__ __launch_bounds__(256, 4)
void local_linear_kernel(const float* __restrict__ x,
                         const unsigned short* __restrict__ Wbf,
                         const float* __restrict__ b,
                         float* __restrict__ out) {
    __shared__ unsigned short xs[BM][LDSP];

    const int bg = blockIdx.x;           // batch block 0..63
    const int fg = blockIdx.y;           // fold group 0..63
    const int row0 = bg * BM;
    const int col0 = fg * (NF * STRIDE_);

    const int t = threadIdx.x;

    // ---- stage x tile (BM x XCOLS) fp32 -> bf16 into LDS ----
    #pragma unroll
    for (int it = 0; it < (BM * (XCOLS / 4)) / 256; ++it) {   // 6 iters
        int i  = t + it * 256;
        int r  = i / (XCOLS / 4);
        int c4 = i - r * (XCOLS / 4);
        int gcol = col0 + c4 * 4;
        float4 v = make_float4(0.f, 0.f, 0.f, 0.f);
        if (gcol < IN_F) {
            v = *reinterpret_cast<const float4*>(x + (size_t)(row0 + r) * IN_F + gcol);
        }
        ushort4 s;
        s.x = f2bf(v.x); s.y = f2bf(v.y); s.z = f2bf(v.z); s.w = f2bf(v.w);
        *reinterpret_cast<ushort4*>(&xs[r][c4 * 4]) = s;
    }
    __syncthreads();

    const int wave = t >> 6;             // 0..3
    const int lane = t & 63;
    const int fold = wave >> 1;          // fold within block
    const int h    = wave & 1;           // feature half (nt base = h*4)
    const int f = fg * NF + fold;
    if (f >= FOLDS) return;              // tail: after sync, safe

    const int l16 = lane & 15;
    const int g   = lane >> 4;

    f32x4 acc[4][4];
    #pragma unroll
    for (int mt = 0; mt < 4; ++mt)
        #pragma unroll
        for (int nt = 0; nt < 4; ++nt)
            acc[mt][nt] = (f32x4){0.f, 0.f, 0.f, 0.f};

    const int fcol = fold * STRIDE_;
    const unsigned short* Wf = Wbf + (size_t)f * (LOCAL_F * KSZ) + (h * 4 * 16) * KSZ;

    #pragma unroll
    for (int ks = 0; ks < 2; ++ks) {
        // W fragment: lane holds W[f][h*64 + nt*16 + l16][ks*32 + g*8 + 0..7]
        bf16x8 wf[4];
        #pragma unroll
        for (int nt = 0; nt < 4; ++nt)
            wf[nt] = *reinterpret_cast<const bf16x8*>(Wf + (nt * 16 + l16) * KSZ + ks * 32 + g * 8);
        // x fragment from LDS
        bf16x8 af[4];
        #pragma unroll
        for (int mt = 0; mt < 4; ++mt)
            af[mt] = *reinterpret_cast<const bf16x8*>(&xs[mt * 16 + l16][fcol + ks * 32 + g * 8]);
        // D = W x X^T : lane holds D[feature = 4g+j][batch = l16]
        #pragma unroll
        for (int mt = 0; mt < 4; ++mt)
            #pragma unroll
            for (int nt = 0; nt < 4; ++nt)
                acc[mt][nt] = __builtin_amdgcn_mfma_f32_16x16x32_bf16(wf[nt], af[mt], acc[mt][nt], 0, 0, 0);
    }

    // ---- epilogue: bias + nontemporal float4 stores ----
    // lane owns batch row (mt*16 + l16), features f*128 + h*64 + nt*16 + 4g + 0..3
    f32x4 bv[4];
    #pragma unroll
    for (int nt = 0; nt < 4; ++nt)
        bv[nt] = *reinterpret_cast<const f32x4*>(b + (size_t)f * LOCAL_F + h * 64 + nt * 16 + 4 * g);

    #pragma unroll
    for (int mt = 0; mt < 4; ++mt) {
        float* orow = out + (size_t)(row0 + mt * 16 + l16) * OUT_F + f * LOCAL_F + h * 64 + 4 * g;
        #pragma unroll
        for (int nt = 0; nt < 4; ++nt) {
            f32x4 v = acc[mt][nt] + bv[nt];
            __builtin_nontemporal_store(v, reinterpret_cast<f32x4*>(orow + nt * 16));
        }
    }
}

extern "C" void kernel_launch(void* const* d_in, const int* in_sizes, int n_in,
                              void* d_out, int out_size, void* d_ws, size_t ws_size,
                              hipStream_t stream) {
    const float* x = (const float*)d_in[0];
    const float* W = (const float*)d_in[1];
    const float* b = (const float*)d_in[2];
    float* out = (float*)d_out;
    unsigned short* Wbf = (unsigned short*)d_ws;

    wprep_kernel<<<(WN / 8 + 255) / 256, 256, 0, stream>>>(W, Wbf);
    dim3 grid(BATCH_ / BM, (FOLDS + NF - 1) / NF);
    local_linear_kernel<<<grid, 256, 0, stream>>>(x, Wbf, b, out);
}